// Round 6
// baseline (433.379 us; speedup 1.0000x reference)
//
#include <hip/hip_runtime.h>
#include <math.h>

#define F_IN 128
#define AH 16
#define ALPHA 0.2f

__device__ __forceinline__ unsigned f2bf_rn(float x) {
    unsigned u = __float_as_uint(x);
    return (u + 0x7fffu + ((u >> 16) & 1u)) >> 16;
}

// ============ K1: h_mini = input @ w_mini + b_mini  AND  sim = bf16(input*deg)
__global__ void k_mini(const float* __restrict__ input,
                       const float* __restrict__ w,
                       const float* __restrict__ b,
                       const float* __restrict__ degree,
                       float* __restrict__ out,
                       unsigned* __restrict__ sim, int n) {
    __shared__ float ws[F_IN * AH];
    __shared__ float rows[16][F_IN + 1];
    __shared__ float dgs[16];
    for (int i = threadIdx.x; i < F_IN * AH; i += blockDim.x) ws[i] = w[i];
    const int base = blockIdx.x * 16;
    for (int idx = threadIdx.x; idx < 16 * F_IN; idx += blockDim.x) {
        const int l = idx >> 7, f = idx & 127;
        const int node = base + l;
        rows[l][f] = (node < n) ? input[(size_t)node * F_IN + f] : 0.f;
    }
    if (threadIdx.x < 16) {
        const int node = base + threadIdx.x;
        dgs[threadIdx.x] = (node < n) ? degree[node] : 0.f;
    }
    __syncthreads();
    {
        const int l = threadIdx.x >> 4;
        const int j = threadIdx.x & 15;
        const int node = base + l;
        if (node < n) {
            float acc = b[j];
            #pragma unroll 8
            for (int f = 0; f < F_IN; ++f) acc += rows[l][f] * ws[f * AH + j];
            out[(size_t)node * AH + j] = acc;
        }
    }
    for (int idx = threadIdx.x; idx < 16 * 64; idx += blockDim.x) {
        const int l = idx >> 6, pr = idx & 63;
        const int node = base + l;
        if (node < n) {
            const float dg = dgs[l];
            const float x = rows[l][2 * pr]     * dg;
            const float y = rows[l][2 * pr + 1] * dg;
            sim[(size_t)node * 64 + pr] = (f2bf_rn(y) << 16) | f2bf_rn(x);
        }
    }
}

// ============ K-prep ======================================================
__global__ void k_prep(const float* __restrict__ lf1_w, const float* __restrict__ ab,
                       float* __restrict__ Cj) {
    const int j = threadIdx.x;
    if (j < AH) {
        float c = 0.f;
        for (int k = 0; k < AH; ++k)
            c += ab[k] * (lf1_w[k * AH + j] + lf1_w[(AH + k) * AH + j]);
        Cj[j] = c;
    }
}

// ============ K2: histogram of src ========================================
__global__ void k_hist(const int* __restrict__ src, int* __restrict__ cnt, int e) {
    const int i = blockIdx.x * blockDim.x + threadIdx.x;
    if (i < e) atomicAdd(&cnt[src[i]], 1);
}

// ============ K3: exclusive scan (+ row_id fill in the add pass) ==========
#define SCAN_B 256
#define SCAN_I 4
__global__ void k_scan_part(const int* __restrict__ cnt, int* __restrict__ excl,
                            int* __restrict__ bsum, int n) {
    __shared__ int sh[SCAN_B];
    const int t = threadIdx.x;
    const int base = blockIdx.x * (SCAN_B * SCAN_I) + t * SCAN_I;
    int v[SCAN_I];
    int s = 0;
    #pragma unroll
    for (int k = 0; k < SCAN_I; ++k) { const int i = base + k; v[k] = (i < n) ? cnt[i] : 0; s += v[k]; }
    sh[t] = s; __syncthreads();
    for (int off = 1; off < SCAN_B; off <<= 1) {
        const int x = (t >= off) ? sh[t - off] : 0;
        __syncthreads();
        sh[t] += x;
        __syncthreads();
    }
    int r = sh[t] - s;
    if (t == SCAN_B - 1) bsum[blockIdx.x] = sh[t];
    #pragma unroll
    for (int k = 0; k < SCAN_I; ++k) { const int i = base + k; if (i < n) excl[i] = r; r += v[k]; }
}
__global__ void k_scan_tops(int* __restrict__ bsum, int nb) {
    __shared__ int sh[SCAN_B];
    const int t = threadIdx.x;
    const int v = (t < nb) ? bsum[t] : 0;
    sh[t] = v; __syncthreads();
    for (int off = 1; off < SCAN_B; off <<= 1) {
        const int x = (t >= off) ? sh[t - off] : 0;
        __syncthreads();
        sh[t] += x;
        __syncthreads();
    }
    if (t < nb) bsum[t] = sh[t] - v;
}
__global__ void k_scan_add_fill(int* __restrict__ excl, const int* __restrict__ bsum,
                                const int* __restrict__ cnt, int* __restrict__ row_id, int n) {
    const int i = blockIdx.x * blockDim.x + threadIdx.x;
    if (i >= n) return;
    const int off = excl[i] + bsum[i >> 10];
    excl[i] = off;
    const int c = cnt[i];
    for (int k = 0; k < c; ++k) row_id[off + k] = i;
}

// ============ K4: scatter (dst,eid) packed, nontemporal ===================
__global__ void k_scatter(const int* __restrict__ src, const int* __restrict__ dst,
                          int* __restrict__ row_cur,
                          unsigned long long* __restrict__ sorted_de, int e) {
    const int i = blockIdx.x * blockDim.x + threadIdx.x;
    if (i >= e) return;
    const int s = src[i];
    const int p = atomicAdd(&row_cur[s], 1);
    const unsigned long long v =
        ((unsigned long long)(unsigned)i << 32) | (unsigned)dst[i];
    __builtin_nontemporal_store(v, sorted_de + p);
}

// ============ K5: edge MLP in CSR-sorted order (all IO coalesced) =========
#define ROW4(base, val) \
    w = Wv[(base) * 4 + 0]; f0  += (val) * w.x; f1  += (val) * w.y; f2  += (val) * w.z; f3  += (val) * w.w; \
    w = Wv[(base) * 4 + 1]; f4  += (val) * w.x; f5  += (val) * w.y; f6  += (val) * w.z; f7  += (val) * w.w; \
    w = Wv[(base) * 4 + 2]; f8  += (val) * w.x; f9  += (val) * w.y; f10 += (val) * w.z; f11 += (val) * w.w; \
    w = Wv[(base) * 4 + 3]; f12 += (val) * w.x; f13 += (val) * w.y; f14 += (val) * w.z; f15 += (val) * w.w;

#define KSTEP(k, hs, hd) { \
    const float df_ = fabsf((hd) - (hs)); float4 w; \
    ROW4((k), (hs)) ROW4((16 + (k)), (hd)) ROW4((32 + (k)), df_) }

#define TAIL(j, fj) { \
    const float w2_ = lf2_w[j]; const float c_ = Cj[j]; \
    acc0 += w2_ * ((fj) > 0.f ? (fj) : ALPHA * (fj)); \
    const float v1_ = (fj) + c_; \
    acc1 += w2_ * (v1_ > 0.f ? v1_ : ALPHA * v1_); }

__global__ __launch_bounds__(256, 4)
void k_mlp(const int* __restrict__ row_id, const int2* __restrict__ sorted_de,
           const float* __restrict__ h,
           const float* __restrict__ lf1_w, const float* __restrict__ lf1_b,
           const float* __restrict__ lf2_w, const float* __restrict__ lf2_b,
           const float* __restrict__ Cj,
           unsigned* __restrict__ fcp, int e) {
    const int i = blockIdx.x * blockDim.x + threadIdx.x;
    if (i >= e) return;
    const int s = row_id[i];
    const int d = sorted_de[i].x;
    const float4* __restrict__ ps = (const float4*)(h + (size_t)s * AH);
    const float4* __restrict__ pd = (const float4*)(h + (size_t)d * AH);
    const float4* __restrict__ Wv = (const float4*)lf1_w;

    float f0  = lf1_b[0],  f1  = lf1_b[1],  f2  = lf1_b[2],  f3  = lf1_b[3];
    float f4  = lf1_b[4],  f5  = lf1_b[5],  f6  = lf1_b[6],  f7  = lf1_b[7];
    float f8  = lf1_b[8],  f9  = lf1_b[9],  f10 = lf1_b[10], f11 = lf1_b[11];
    float f12 = lf1_b[12], f13 = lf1_b[13], f14 = lf1_b[14], f15 = lf1_b[15];

    float4 a, b4;
    a = ps[0]; b4 = pd[0];
    KSTEP(0,  a.x, b4.x) KSTEP(1,  a.y, b4.y) KSTEP(2,  a.z, b4.z) KSTEP(3,  a.w, b4.w)
    a = ps[1]; b4 = pd[1];
    KSTEP(4,  a.x, b4.x) KSTEP(5,  a.y, b4.y) KSTEP(6,  a.z, b4.z) KSTEP(7,  a.w, b4.w)
    a = ps[2]; b4 = pd[2];
    KSTEP(8,  a.x, b4.x) KSTEP(9,  a.y, b4.y) KSTEP(10, a.z, b4.z) KSTEP(11, a.w, b4.w)
    a = ps[3]; b4 = pd[3];
    KSTEP(12, a.x, b4.x) KSTEP(13, a.y, b4.y) KSTEP(14, a.z, b4.z) KSTEP(15, a.w, b4.w)

    float acc0 = lf2_b[0], acc1 = lf2_b[0];
    TAIL(0, f0)  TAIL(1, f1)  TAIL(2, f2)   TAIL(3, f3)
    TAIL(4, f4)  TAIL(5, f5)  TAIL(6, f6)   TAIL(7, f7)
    TAIL(8, f8)  TAIL(9, f9)  TAIL(10, f10) TAIL(11, f11)
    TAIL(12, f12) TAIL(13, f13) TAIL(14, f14) TAIL(15, f15)

    const float fc0 = 1.f / (1.f + expf(-acc0));
    const float fc1 = 1.f / (1.f + expf(-acc1));
    fcp[i] = (f2bf_rn(fc1) << 16) | f2bf_rn(fc0);   // coalesced packed store
}

// ============ K6: per-node factor (row-sum of packed fc0) =================
__global__ void k_factor(const int* __restrict__ row_end, const int* __restrict__ cnt,
                         const unsigned* __restrict__ fcp, float* __restrict__ factor, int n) {
    const int i = blockIdx.x * blockDim.x + threadIdx.x;
    if (i >= n) return;
    const int end = row_end[i];
    const int c = cnt[i];
    float s = 0.f;
    for (int p = end - c; p < end; ++p) s += __uint_as_float(fcp[p] << 16);
    factor[i] = s / fmaxf((float)c, 1.f);
}

// ============ K7: fused ef + row-sum + SpMM + final combine ===============
__global__ void k_spmm_final(const int* __restrict__ row_end, const int* __restrict__ cnt,
                             const int2* __restrict__ sorted_de,
                             const unsigned* __restrict__ fcp,
                             const float* __restrict__ factor,
                             const unsigned* __restrict__ sim,
                             const float* __restrict__ input,
                             const float* __restrict__ degree,
                             const float* __restrict__ adj_row,
                             float* __restrict__ out_h, float* __restrict__ ef_out, int n) {
    __shared__ float2 sh[256];            // per-wave 64-entry slot: (ef, bits(dst))
    const int wid  = (blockIdx.x * blockDim.x + threadIdx.x) >> 6;
    const int lane = threadIdx.x & 63;
    const int sbase = threadIdx.x & ~63;
    if (wid >= n) return;
    const int end = row_end[wid];
    const int beg = end - cnt[wid];
    const float fnode = factor[wid];
    float acc0 = 0.f, acc1 = 0.f, efl = 0.f;
    for (int base = beg; base < end; base += 64) {
        const int rem = end - base;
        const int mm = rem < 64 ? rem : 64;
        float ef = 0.f; int dl = 0;
        if (lane < mm) {
            const int2 de = sorted_de[base + lane];
            const float fc1 = __uint_as_float(fcp[base + lane] & 0xffff0000u);
            ef = fnode * factor[de.x] * fc1;
            dl = de.x;
            __builtin_nontemporal_store(ef, ef_out + de.y);
        }
        efl += ef;
        sh[sbase + lane] = make_float2(ef, __int_as_float(dl));
        for (int j = 0; j < mm; j += 8) {
            float2 t0 = sh[sbase + j + 0];
            float2 t1 = sh[sbase + j + 1];
            float2 t2 = sh[sbase + j + 2];
            float2 t3 = sh[sbase + j + 3];
            float2 t4 = sh[sbase + j + 4];
            float2 t5 = sh[sbase + j + 5];
            float2 t6 = sh[sbase + j + 6];
            float2 t7 = sh[sbase + j + 7];
            const unsigned u0 = sim[(size_t)__float_as_int(t0.y) * 64 + lane];
            const unsigned u1 = sim[(size_t)__float_as_int(t1.y) * 64 + lane];
            const unsigned u2 = sim[(size_t)__float_as_int(t2.y) * 64 + lane];
            const unsigned u3 = sim[(size_t)__float_as_int(t3.y) * 64 + lane];
            const unsigned u4 = sim[(size_t)__float_as_int(t4.y) * 64 + lane];
            const unsigned u5 = sim[(size_t)__float_as_int(t5.y) * 64 + lane];
            const unsigned u6 = sim[(size_t)__float_as_int(t6.y) * 64 + lane];
            const unsigned u7 = sim[(size_t)__float_as_int(t7.y) * 64 + lane];
            acc0 += t0.x * __uint_as_float(u0 << 16);
            acc1 += t0.x * __uint_as_float(u0 & 0xffff0000u);
            acc0 += t1.x * __uint_as_float(u1 << 16);
            acc1 += t1.x * __uint_as_float(u1 & 0xffff0000u);
            acc0 += t2.x * __uint_as_float(u2 << 16);
            acc1 += t2.x * __uint_as_float(u2 & 0xffff0000u);
            acc0 += t3.x * __uint_as_float(u3 << 16);
            acc1 += t3.x * __uint_as_float(u3 & 0xffff0000u);
            acc0 += t4.x * __uint_as_float(u4 << 16);
            acc1 += t4.x * __uint_as_float(u4 & 0xffff0000u);
            acc0 += t5.x * __uint_as_float(u5 << 16);
            acc1 += t5.x * __uint_as_float(u5 & 0xffff0000u);
            acc0 += t6.x * __uint_as_float(u6 << 16);
            acc1 += t6.x * __uint_as_float(u6 & 0xffff0000u);
            acc0 += t7.x * __uint_as_float(u7 << 16);
            acc1 += t7.x * __uint_as_float(u7 & 0xffff0000u);
        }
    }
    for (int off = 32; off > 0; off >>= 1) efl += __shfl_xor(efl, off);
    const float aggr = efl / adj_row[wid];
    const float dg = degree[wid];
    const float2 inn = *(const float2*)(input + (size_t)wid * F_IN + 2 * lane);
    float2 o;
    o.x = acc0 * dg + (1.f - aggr) * inn.x;
    o.y = acc1 * dg + (1.f - aggr) * inn.y;
    *(float2*)(out_h + (size_t)wid * F_IN + 2 * lane) = o;
}

extern "C" void kernel_launch(void* const* d_in, const int* in_sizes, int n_in,
                              void* d_out, int out_size, void* d_ws, size_t ws_size,
                              hipStream_t stream) {
    const float* input   = (const float*)d_in[0];
    const int*   edges   = (const int*)  d_in[1];
    const float* adj_row = (const float*)d_in[3];
    const float* degree  = (const float*)d_in[4];
    const float* w_mini  = (const float*)d_in[5];
    const float* b_mini  = (const float*)d_in[6];
    const float* ab      = (const float*)d_in[7];
    const float* lf1_w   = (const float*)d_in[8];
    const float* lf1_b   = (const float*)d_in[9];
    const float* lf2_w   = (const float*)d_in[10];
    const float* lf2_b   = (const float*)d_in[11];

    const int N = in_sizes[0] / F_IN;
    const int E = in_sizes[1] / 2;
    const int* src = edges;
    const int* dst = edges + E;

    float* final_h = (float*)d_out;
    float* ef_out  = (float*)d_out + (size_t)N * F_IN;

    // workspace layout (4-byte words; total ~= round-4's proven footprint)
    float*    h_mini    = (float*)d_ws;                    // N*16
    unsigned* fcp       = (unsigned*)(h_mini + (size_t)N * AH); // E packed (fc0,fc1) bf16
    float*    factor    = (float*)(fcp + E);               // N
    float*    Cj        = factor + N;                      // 16
    int*      cnt       = (int*)(Cj + 16);                 // N
    int*      row_cur   = cnt + N;                         // N
    int*      bsum      = row_cur + N;                     // 1024
    int*      row_id    = bsum + 1024;                     // E
    unsigned long long* sorted_de = (unsigned long long*)(row_id + E); // E (dst|eid<<32)
    unsigned* sim       = (unsigned*)(sorted_de + E);      // N*64 bf16 pairs

    hipMemsetAsync(cnt, 0, (size_t)N * sizeof(int), stream);

    k_mini<<<(N + 15) / 16, 256, 0, stream>>>(input, w_mini, b_mini, degree, h_mini, sim, N);
    k_prep<<<1, 64, 0, stream>>>(lf1_w, ab, Cj);
    k_hist<<<(E + 255) / 256, 256, 0, stream>>>(src, cnt, E);
    {
        const int nb = (N + SCAN_B * SCAN_I - 1) / (SCAN_B * SCAN_I);
        k_scan_part<<<nb, SCAN_B, 0, stream>>>(cnt, row_cur, bsum, N);
        k_scan_tops<<<1, SCAN_B, 0, stream>>>(bsum, nb);
        k_scan_add_fill<<<(N + 255) / 256, 256, 0, stream>>>(row_cur, bsum, cnt, row_id, N);
    }
    k_scatter<<<(E + 255) / 256, 256, 0, stream>>>(src, dst, row_cur, sorted_de, E);
    k_mlp<<<(E + 255) / 256, 256, 0, stream>>>(row_id, (const int2*)sorted_de, h_mini,
                                               lf1_w, lf1_b, lf2_w, lf2_b, Cj, fcp, E);
    k_factor<<<(N + 255) / 256, 256, 0, stream>>>(row_cur, cnt, fcp, factor, N);
    k_spmm_final<<<(N * 64 + 255) / 256, 256, 0, stream>>>(row_cur, cnt, (const int2*)sorted_de,
                                                           fcp, factor, sim, input, degree,
                                                           adj_row, final_h, ef_out, N);
}